// Round 5
// baseline (122.909 us; speedup 1.0000x reference)
//
#include <hip/hip_runtime.h>
#include <stdint.h>

#define BATCH 8
#define CIN   64
#define DH    32
#define NTOK  4096
#define LOG2E 1.4426950408889634f

typedef float    f4   __attribute__((ext_vector_type(4)));
typedef short    s8v  __attribute__((ext_vector_type(8)));
typedef uint32_t u32;
typedef uint32_t u32x2 __attribute__((ext_vector_type(2)));
typedef uint32_t u32x4 __attribute__((ext_vector_type(4)));

static __device__ __forceinline__ short f2bf(float f) {       // RNE
    union { float f; u32 u; } c; c.f = f;
    u32 u = c.u;
    u32 r = (u + 0x7fffu + ((u >> 16) & 1u)) >> 16;
    return (short)(r & 0xffffu);
}
static __device__ __forceinline__ u32 pk2(float a, float b) { // RNE pack
    return (u32)(uint16_t)f2bf(a) | ((u32)(uint16_t)f2bf(b) << 16);
}
static __device__ __forceinline__ u32 pktr(float a, float b) { // truncate pack (fast)
    union { float f; u32 u; } ca, cb; ca.f = a; cb.f = b;
#if __has_builtin(__builtin_amdgcn_perm)
    return __builtin_amdgcn_perm(cb.u, ca.u, 0x07060302u);
#else
    return (cb.u & 0xffff0000u) | (ca.u >> 16);
#endif
}
static __device__ __forceinline__ float bfhi(u32 u) {
    union { u32 u; float f; } c; c.u = u & 0xffff0000u; return c.f;
}
static __device__ __forceinline__ float bflo(u32 u) {
    union { u32 u; float f; } c; c.u = u << 16; return c.f;
}

// ---------------------------------------------------------------------------
// Kernel 1: MFMA QKV projection (unchanged from round 4 — passed).
// ---------------------------------------------------------------------------
__global__ __launch_bounds__(256) void proj_kernel(
    const float* __restrict__ h,
    const float* __restrict__ wq, const float* __restrict__ bq,
    const float* __restrict__ wk, const float* __restrict__ bk,
    const float* __restrict__ wv, const float* __restrict__ bv,
    short* __restrict__ qbf, short* __restrict__ kbf, short* __restrict__ vp)
{
    __shared__ short xT [64 * 72];   // [n_local][c] bf16
    __shared__ short wqs[32 * 72];   // [o][c] bf16 (pre-scaled by log2e)
    __shared__ short wks[32 * 72];
    __shared__ short wvs[64 * 72];
    __shared__ short vls2[64 * 68];  // [row=cid2*32+qq*8+j][ch], pad 68
    __shared__ float bqs[32], bks[32], bvs[64];

    const int t   = threadIdx.x;
    const int b   = blockIdx.x;
    const int nt0 = blockIdx.y * 64;

    { // stage x tile: coalesced global reads, bf16 transpose into LDS
        const int c  = t >> 2;
        const int ng = (t & 3) * 16;
        const float* src = h + ((size_t)(b * CIN + c)) * NTOK + nt0 + ng;
        f4 x0 = *(const f4*)(src + 0);
        f4 x1 = *(const f4*)(src + 4);
        f4 x2 = *(const f4*)(src + 8);
        f4 x3 = *(const f4*)(src + 12);
        #pragma unroll
        for (int i = 0; i < 4; ++i) {
            xT[(ng + 0  + i) * 72 + c] = f2bf(x0[i]);
            xT[(ng + 4  + i) * 72 + c] = f2bf(x1[i]);
            xT[(ng + 8  + i) * 72 + c] = f2bf(x2[i]);
            xT[(ng + 12 + i) * 72 + c] = f2bf(x3[i]);
        }
    }
    for (int idx = t; idx < 2048; idx += 256) {
        int o = idx >> 6, c = idx & 63;
        wqs[o * 72 + c] = f2bf(wq[idx] * LOG2E);
        wks[o * 72 + c] = f2bf(wk[idx]);
    }
    for (int idx = t; idx < 4096; idx += 256)
        wvs[(idx >> 6) * 72 + (idx & 63)] = f2bf(wv[idx]);
    if (t < 32) { bqs[t] = bq[t] * LOG2E; bks[t] = bk[t]; }
    if (t < 64) bvs[t] = bv[t];
    __syncthreads();

    const int w    = t >> 6;
    const int ln   = t & 15;
    const int quad = (t >> 4) & 3;
    const int nl   = w * 16 + ln;
    const int n    = nt0 + nl;
    const f4 zf4 = {0.f, 0.f, 0.f, 0.f};

    const s8v xb0 = *(const s8v*)&xT[nl * 72 + quad * 8];
    const s8v xb1 = *(const s8v*)&xT[nl * 72 + 32 + quad * 8];

    #pragma unroll
    for (int ot = 0; ot < 2; ++ot) {
        s8v a0 = *(const s8v*)&wqs[(ot * 16 + ln) * 72 + quad * 8];
        s8v a1 = *(const s8v*)&wqs[(ot * 16 + ln) * 72 + 32 + quad * 8];
        f4 d = __builtin_amdgcn_mfma_f32_16x16x32_bf16(a0, xb0, zf4, 0, 0, 0);
        d     = __builtin_amdgcn_mfma_f32_16x16x32_bf16(a1, xb1, d,  0, 0, 0);
        f4 bb = *(const f4*)&bqs[ot * 16 + quad * 4];
        u32x2 pw; pw[0] = pk2(d[0] + bb[0], d[1] + bb[1]);
                  pw[1] = pk2(d[2] + bb[2], d[3] + bb[3]);
        *(u32x2*)(qbf + ((size_t)(b * NTOK + n)) * DH + ot * 16 + quad * 4) = pw;

        s8v c0 = *(const s8v*)&wks[(ot * 16 + ln) * 72 + quad * 8];
        s8v c1 = *(const s8v*)&wks[(ot * 16 + ln) * 72 + 32 + quad * 8];
        f4 e = __builtin_amdgcn_mfma_f32_16x16x32_bf16(c0, xb0, zf4, 0, 0, 0);
        e     = __builtin_amdgcn_mfma_f32_16x16x32_bf16(c1, xb1, e,  0, 0, 0);
        f4 kb = *(const f4*)&bks[ot * 16 + quad * 4];
        u32x2 kw; kw[0] = pk2(e[0] + kb[0], e[1] + kb[1]);
                  kw[1] = pk2(e[2] + kb[2], e[3] + kb[3]);
        *(u32x2*)(kbf + ((size_t)(b * NTOK + n)) * DH + ot * 16 + quad * 4) = kw;
    }

    {
        const int p    = nl & 31;
        const int row  = (nl >> 5) * 32 + ((p >> 2) & 3) * 8
                       + (p >> 4) * 4 + (p & 3);
        short* vrow = &vls2[row * 68];
        #pragma unroll
        for (int ot = 0; ot < 4; ++ot) {
            s8v a0 = *(const s8v*)&wvs[(ot * 16 + ln) * 72 + quad * 8];
            s8v a1 = *(const s8v*)&wvs[(ot * 16 + ln) * 72 + 32 + quad * 8];
            f4 d = __builtin_amdgcn_mfma_f32_16x16x32_bf16(a0, xb0, zf4, 0, 0, 0);
            d     = __builtin_amdgcn_mfma_f32_16x16x32_bf16(a1, xb1, d,  0, 0, 0);
            const int ch = ot * 16 + quad * 4;
            u32x2 pw;
            pw[0] = pk2(d[0] + bvs[ch],     d[1] + bvs[ch + 1]);
            pw[1] = pk2(d[2] + bvs[ch + 2], d[3] + bvs[ch + 3]);
            *(u32x2*)&vrow[ch] = pw;
        }
    }
    __syncthreads();

    {
        const int g = t >> 5;
        const int r = t & 31;
        short tmp[16];
        #pragma unroll
        for (int j = 0; j < 8; ++j)
            #pragma unroll
            for (int cc = 0; cc < 2; ++cc)
                tmp[cc * 8 + j] = vls2[(g * 8 + j) * 68 + r * 2 + cc];
        u32x4* dst = (u32x4*)(vp + ((size_t)(b * 128 + blockIdx.y * 2) * 4) * 64 * 8);
        #pragma unroll
        for (int i = 0; i < 2; ++i)
            dst[t * 2 + i] = ((const u32x4*)tmp)[i];
    }
}

// ---------------------------------------------------------------------------
// Kernel 2: flash attention with LDS-shared K/V tiles + pipelined staging.
// Block: 512 thr = 8 waves = 2 query-groups (qg) x 4 key-quarters (kh).
// Block covers 128 queries x all 4096 keys. grid (8, 32) = 256 blocks.
// Per 32-key tile: 6 KB (K 2 KB + V 4 KB) staged once per kh-stream, shared
// by that stream's 2 waves -> L2 reads 393 MB -> 196 MB vs round 4.
// Pipeline: barrier / ds_write(r) / barrier / issue loads(it+1) / compute(it)
// so the compiler's vmcnt(0)-before-barrier doesn't drain the prefetch.
// ---------------------------------------------------------------------------
__global__ __launch_bounds__(512, 2) void attn_kernel(
    const float* __restrict__ h,  const float* __restrict__ wz,
    const float* __restrict__ bz,
    const short* __restrict__ qbf, const short* __restrict__ kbf,
    const short* __restrict__ vp,  float* __restrict__ out)
{
    __shared__ short kst[4 * 3072];    // 4 kh-streams x 6144 B tile
    __shared__ short accb[128 * 72];   // combine slot (bf16), 18.4 KB
    __shared__ short zbuf[128 * 72];   // normalized z [query][ch], 18.4 KB
    __shared__ float lbuf[128];        // partial l slot

    const int b    = blockIdx.x;           // XCD-affine: linear%8 == b
    const int qb0  = blockIdx.y * 128;
    const int tid  = threadIdx.x;
    const int w    = tid >> 6;
    const int lane = tid & 63;
    const int ln   = lane & 15;
    const int quad = lane >> 4;
    const int qg   = w & 1;                // query group (64 q)
    const int kh   = w >> 1;               // key quarter (1024 keys)
    const f4 zf4 = {0.f, 0.f, 0.f, 0.f};

    short* stage = &kst[kh * 3072];        // this stream's tile (shorts)
    const short* kb = kbf + ((size_t)b * NTOK + kh * 1024) * DH;
    const short* vb = vp  + (size_t)(b * 128 + kh * 32) * 4 * 64 * 8;

    // Q fragments (B-operand): B[d=quad*8+j][n=ln]
    s8v qf[4];
    #pragma unroll
    for (int f = 0; f < 4; ++f)
        qf[f] = *(const s8v*)(qbf +
            ((size_t)(b * NTOK + qb0 + qg * 64 + f * 16 + ln)) * DH + quad * 8);

    f4 acc[4][4];
    f4 accl[4];
    #pragma unroll
    for (int f = 0; f < 4; ++f) {
        accl[f] = zf4;
        #pragma unroll
        for (int ct = 0; ct < 4; ++ct) acc[f][ct] = zf4;
    }
    s8v ones;
    #pragma unroll
    for (int j = 0; j < 8; ++j) ones[j] = (short)0x3F80;   // bf16 1.0

    // prologue: load tile 0 into registers (3 x dwordx4 per lane per wave)
    u32x4 r[3];
    #pragma unroll
    for (int j = 0; j < 3; ++j) {
        const int c = qg * 3 + j;          // chunk 0..5 of the 6 KB tile
        const short* src = (c < 2) ? (kb + c * 512 + lane * 8)
                                   : (vb + (c - 2) * 512 + lane * 8);
        r[j] = *(const u32x4*)src;
    }

    for (int it = 0; it < 32; ++it) {
        __syncthreads();                   // stream consumers done with stage
        #pragma unroll
        for (int j = 0; j < 3; ++j) {
            const int c = qg * 3 + j;
            *(u32x4*)&stage[c * 512 + lane * 8] = r[j];
        }
        __syncthreads();                   // stage(it) visible to both waves
        if (it + 1 < 32) {                 // prefetch overlaps compute below
            const short* ks = kb + (it + 1) * 1024;
            const short* vs = vb + (it + 1) * 2048;
            #pragma unroll
            for (int j = 0; j < 3; ++j) {
                const int c = qg * 3 + j;
                const short* src = (c < 2) ? (ks + c * 512 + lane * 8)
                                           : (vs + (c - 2) * 512 + lane * 8);
                r[j] = *(const u32x4*)src;
            }
        }

        // K frags: A[key=ln(+16)][d=quad*8+j]; V frags: A[c=ct*16+ln][slot]
        s8v kk0 = *(const s8v*)&stage[ln * 32 + quad * 8];
        s8v kk1 = *(const s8v*)&stage[(16 + ln) * 32 + quad * 8];
        s8v v0 = *(const s8v*)&stage[1024 + (quad * 64 +  0 + ln) * 8];
        s8v v1 = *(const s8v*)&stage[1024 + (quad * 64 + 16 + ln) * 8];
        s8v v2 = *(const s8v*)&stage[1024 + (quad * 64 + 32 + ln) * 8];
        s8v v3 = *(const s8v*)&stage[1024 + (quad * 64 + 48 + ln) * 8];

        #pragma unroll
        for (int f = 0; f < 4; ++f) {
            f4 sa = __builtin_amdgcn_mfma_f32_16x16x32_bf16(kk0, qf[f], zf4, 0, 0, 0);
            f4 sb = __builtin_amdgcn_mfma_f32_16x16x32_bf16(kk1, qf[f], zf4, 0, 0, 0);
            f4 ea, eb;
            #pragma unroll
            for (int rr = 0; rr < 4; ++rr) {
                ea[rr] = __builtin_amdgcn_exp2f(sa[rr]);   // scores pre-scaled by log2e
                eb[rr] = __builtin_amdgcn_exp2f(sb[rr]);
            }
            u32x4 pd;
            pd[0] = pktr(ea[0], ea[1]); pd[1] = pktr(ea[2], ea[3]);
            pd[2] = pktr(eb[0], eb[1]); pd[3] = pktr(eb[2], eb[3]);
            s8v pf = __builtin_bit_cast(s8v, pd);

            accl[f]   = __builtin_amdgcn_mfma_f32_16x16x32_bf16(ones, pf, accl[f],   0, 0, 0);
            acc[f][0] = __builtin_amdgcn_mfma_f32_16x16x32_bf16(v0,   pf, acc[f][0], 0, 0, 0);
            acc[f][1] = __builtin_amdgcn_mfma_f32_16x16x32_bf16(v1,   pf, acc[f][1], 0, 0, 0);
            acc[f][2] = __builtin_amdgcn_mfma_f32_16x16x32_bf16(v2,   pf, acc[f][2], 0, 0, 0);
            acc[f][3] = __builtin_amdgcn_mfma_f32_16x16x32_bf16(v3,   pf, acc[f][3], 0, 0, 0);
        }
    }

    // ---- 4-way combine (pure adds, max-free), 3 phases through one slot ----
    for (int ph = 1; ph < 4; ++ph) {
        if (kh == ph) {
            #pragma unroll
            for (int f = 0; f < 4; ++f) {
                const int row = qg * 64 + f * 16 + ln;
                if (quad == 0) lbuf[row] = accl[f][0];
                #pragma unroll
                for (int ct = 0; ct < 4; ++ct) {
                    u32x2 pw;
                    pw[0] = pk2(acc[f][ct][0], acc[f][ct][1]);
                    pw[1] = pk2(acc[f][ct][2], acc[f][ct][3]);
                    *(u32x2*)&accb[row * 72 + ct * 16 + quad * 4] = pw;
                }
            }
        }
        __syncthreads();
        if (kh == 0) {
            #pragma unroll
            for (int f = 0; f < 4; ++f) {
                const int row = qg * 64 + f * 16 + ln;
                accl[f][0] += lbuf[row];
                #pragma unroll
                for (int ct = 0; ct < 4; ++ct) {
                    u32x2 pw = *(const u32x2*)&accb[row * 72 + ct * 16 + quad * 4];
                    acc[f][ct][0] += bflo(pw[0]); acc[f][ct][1] += bfhi(pw[0]);
                    acc[f][ct][2] += bflo(pw[1]); acc[f][ct][3] += bfhi(pw[1]);
                }
            }
        }
        __syncthreads();
    }

    // ---- normalize + zbuf (kh0 waves own the full sums) ----
    if (kh == 0) {
        #pragma unroll
        for (int f = 0; f < 4; ++f) {
            const float rl = __builtin_amdgcn_rcpf(accl[f][0]);
            const int row = qg * 64 + f * 16 + ln;
            #pragma unroll
            for (int ct = 0; ct < 4; ++ct) {
                u32x2 pw;
                pw[0] = pk2(acc[f][ct][0] * rl, acc[f][ct][1] * rl);
                pw[1] = pk2(acc[f][ct][2] * rl, acc[f][ct][3] * rl);
                *(u32x2*)&zbuf[row * 72 + ct * 16 + quad * 4] = pw;
            }
        }
    }
    __syncthreads();

    // ---- out-projection: wave w -> o-tile (w&3), query group (w>>2) ----
    {
        const int ot = w & 3, qg2 = w >> 2;
        s8v wzf[2];
        #pragma unroll
        for (int half = 0; half < 2; ++half) {
            const float* wp = wz + (ot * 16 + ln) * 64 + half * 32 + quad * 8;
            f4 wa = *(const f4*)wp;
            f4 wb = *(const f4*)(wp + 4);
            u32x4 tt;
            tt[0] = pk2(wa[0], wa[1]); tt[1] = pk2(wa[2], wa[3]);
            tt[2] = pk2(wb[0], wb[1]); tt[3] = pk2(wb[2], wb[3]);
            wzf[half] = __builtin_bit_cast(s8v, tt);
        }
        f4 bzv = *(const f4*)(bz + ot * 16 + quad * 4);
        #pragma unroll
        for (int fi = 0; fi < 4; ++fi) {
            const int row = qg2 * 64 + fi * 16 + ln;
            s8v z0 = *(const s8v*)&zbuf[row * 72 + quad * 8];
            s8v z1 = *(const s8v*)&zbuf[row * 72 + 32 + quad * 8];
            f4 oa = __builtin_amdgcn_mfma_f32_16x16x32_bf16(wzf[0], z0, zf4, 0, 0, 0);
            oa     = __builtin_amdgcn_mfma_f32_16x16x32_bf16(wzf[1], z1, oa,  0, 0, 0);
            #pragma unroll
            for (int rr = 0; rr < 4; ++rr) {
                size_t idx = ((size_t)(b * CIN + ot * 16 + quad * 4 + rr)) * NTOK
                           + qb0 + row;
                out[idx] = oa[rr] + bzv[rr] + h[idx];
            }
        }
    }
}

extern "C" void kernel_launch(void* const* d_in, const int* in_sizes, int n_in,
                              void* d_out, int out_size, void* d_ws, size_t ws_size,
                              hipStream_t stream) {
    (void)in_sizes; (void)n_in; (void)out_size; (void)ws_size;
    const float* h  = (const float*)d_in[0];
    const float* wq = (const float*)d_in[1];
    const float* bq = (const float*)d_in[2];
    const float* wk = (const float*)d_in[3];
    const float* bk = (const float*)d_in[4];
    const float* wv = (const float*)d_in[5];
    const float* bv = (const float*)d_in[6];
    const float* wz = (const float*)d_in[7];
    const float* bz = (const float*)d_in[8];
    float* out = (float*)d_out;

    short* qbf = (short*)d_ws;                                // 8*4096*32
    short* kbf = qbf + (size_t)BATCH * NTOK * DH;             // 8*4096*32
    short* vpw = kbf + (size_t)BATCH * NTOK * DH;             // 8*4096*64

    proj_kernel<<<dim3(8, 64), dim3(256), 0, stream>>>(
        h, wq, bq, wk, bk, wv, bv, qbf, kbf, vpw);
    attn_kernel<<<dim3(8, 32), dim3(512), 0, stream>>>(
        h, wz, bz, qbf, kbf, vpw, out);
}